// Round 3
// baseline (5256.917 us; speedup 1.0000x reference)
//
#include <hip/hip_runtime.h>

#define NNODE 6144
#define FEATD 512
#define HIDD  512
#define NCLSD 64
#define LALPHA 0.2f

__device__ __forceinline__ float lrelu(float x){ return x > 0.f ? x : LALPHA * x; }

// ---------------- C[M,Nc] = A[M,K] @ B[K,Nc]  (dumb fp32) ----------------
__global__ void k_mm(const float* __restrict__ A, const float* __restrict__ B,
                     float* __restrict__ C, int M, int K, int Nc){
    int idx = blockIdx.x * blockDim.x + threadIdx.x;
    if (idx >= M * Nc) return;
    int r = idx / Nc, c = idx - r * Nc;
    const float* a = A + (size_t)r * K;
    float acc = 0.f;
    for (int k = 0; k < K; k++) acc += a[k] * B[(size_t)k * Nc + c];
    C[idx] = acc;
}

// ---------------- o1[i]=dot(A[i],v1); o2[i]=dot(A[i],v2)  (one wave/row) ----------------
__global__ void k_rowvec2_f32(const float* __restrict__ A, const float* __restrict__ v1,
                              const float* __restrict__ v2, float* __restrict__ o1,
                              float* __restrict__ o2, int K){
    int row  = (blockIdx.x * blockDim.x + threadIdx.x) >> 6;
    int lane = threadIdx.x & 63;
    const float* r = A + (size_t)row * K;
    float s1 = 0.f, s2 = 0.f;
    for (int c = lane; c < K; c += 64){ float x = r[c]; s1 += x * v1[c]; s2 += x * v2[c]; }
    #pragma unroll
    for (int m = 32; m; m >>= 1){ s1 += __shfl_xor(s1, m); s2 += __shfl_xor(s2, m); }
    if (lane == 0){ o1[row] = s1; o2[row] = s2; }
}

// ---------------- GAT layer 1 oracle: res = elu(softmax_mask(lrelu(e1_i+e2_j)) @ Wh) ----------------
// one block (512 thr) per query row i; thread owns output channel c = tid.
__global__ __launch_bounds__(512) void k_gat1_oracle(const int* __restrict__ adj,
        const float* __restrict__ e1, const float* __restrict__ e2,
        const float* __restrict__ Wh, float* __restrict__ res){
    __shared__ float pbuf[512];
    __shared__ float red[8];
    int i = blockIdx.x, tid = threadIdx.x;
    const int* adjp = adj + (size_t)i * NNODE;
    float e1i = e1[i];
    // pass A: true masked max
    float m = -3.0e38f;
    for (int j = tid; j < NNODE; j += 512)
        if (adjp[j] > 0) m = fmaxf(m, lrelu(e1i + e2[j]));
    #pragma unroll
    for (int o = 32; o; o >>= 1) m = fmaxf(m, __shfl_xor(m, o));
    if ((tid & 63) == 0) red[tid >> 6] = m;
    __syncthreads();
    float mm = red[0];
    #pragma unroll
    for (int q = 1; q < 8; q++) mm = fmaxf(mm, red[q]);
    m = mm;
    __syncthreads();
    // pass B: p staged per 512-tile in LDS; unnormalized accumulate
    float den = 0.f, acc = 0.f;
    for (int j0 = 0; j0 < NNODE; j0 += 512){
        int j = j0 + tid;
        float p = 0.f;
        if (adjp[j] > 0) p = expf(lrelu(e1i + e2[j]) - m);
        pbuf[tid] = p; den += p;
        __syncthreads();
        for (int jj = 0; jj < 512; jj++)
            acc += pbuf[jj] * Wh[(size_t)(j0 + jj) * HIDD + tid];
        __syncthreads();
    }
    #pragma unroll
    for (int o = 32; o; o >>= 1) den += __shfl_xor(den, o);
    if ((tid & 63) == 0) red[tid >> 6] = den;
    __syncthreads();
    float dtot = 0.f;
    #pragma unroll
    for (int q = 0; q < 8; q++) dtot += red[q];
    float v = acc / dtot;
    v = v > 0.f ? v : expm1f(v);          // elu
    res[(size_t)i * HIDD + tid] = v;
}

// ---------------- GAT layer 2 oracle (+tree extra), no elu ----------------
// one block (512 thr) per row; threads 0..63 own the 64 classes for accumulation.
__global__ __launch_bounds__(512) void k_gat2_oracle(const int* __restrict__ adj,
        const float* __restrict__ o1, const float* __restrict__ o2,
        const float* __restrict__ t1, const float* __restrict__ t2,
        const float* __restrict__ Wh2, float* __restrict__ out2){
    __shared__ float pbuf[512];
    __shared__ float red[8];
    int i = blockIdx.x, tid = threadIdx.x;
    const int* adjp = adj + (size_t)i * NNODE;
    float o1i = o1[i], t1i = t1[i];
    float m = -3.0e38f;
    for (int j = tid; j < NNODE; j += 512)
        if (adjp[j] > 0) m = fmaxf(m, lrelu(o1i + o2[j]) + lrelu(t1i + t2[j]));
    #pragma unroll
    for (int o = 32; o; o >>= 1) m = fmaxf(m, __shfl_xor(m, o));
    if ((tid & 63) == 0) red[tid >> 6] = m;
    __syncthreads();
    float mm = red[0];
    #pragma unroll
    for (int q = 1; q < 8; q++) mm = fmaxf(mm, red[q]);
    m = mm;
    __syncthreads();
    float den = 0.f, acc = 0.f;
    for (int j0 = 0; j0 < NNODE; j0 += 512){
        int j = j0 + tid;
        float p = 0.f;
        if (adjp[j] > 0) p = expf(lrelu(o1i + o2[j]) + lrelu(t1i + t2[j]) - m);
        pbuf[tid] = p; den += p;
        __syncthreads();
        if (tid < 64)
            for (int jj = 0; jj < 512; jj++)
                acc += pbuf[jj] * Wh2[(size_t)(j0 + jj) * NCLSD + tid];
        __syncthreads();
    }
    #pragma unroll
    for (int o = 32; o; o >>= 1) den += __shfl_xor(den, o);
    if ((tid & 63) == 0) red[tid >> 6] = den;
    __syncthreads();
    float dtot = 0.f;
    #pragma unroll
    for (int q = 0; q < 8; q++) dtot += red[q];
    if (tid < 64) out2[(size_t)i * NCLSD + tid] = acc / dtot;
}

// ---------------- row-wise log_softmax over 64 classes (one wave/row) ----------------
__global__ void k_logsoftmax(const float* __restrict__ out2, float* __restrict__ out){
    int w = threadIdx.x >> 6, l = threadIdx.x & 63;
    int row = blockIdx.x * 4 + w;
    float v = out2[(size_t)row * NCLSD + l];
    float mx = v;
    #pragma unroll
    for (int o = 32; o; o >>= 1) mx = fmaxf(mx, __shfl_xor(mx, o));
    float ex = expf(v - mx);
    #pragma unroll
    for (int o = 32; o; o >>= 1) ex += __shfl_xor(ex, o);
    out[(size_t)row * NCLSD + l] = v - mx - logf(ex);
}

// ---------------- launch ----------------
extern "C" void kernel_launch(void* const* d_in, const int* in_sizes, int n_in,
                              void* d_out, int out_size, void* d_ws, size_t ws_size,
                              hipStream_t stream){
    const float* X   = (const float*)d_in[0];
    const int*   adj = (const int*)d_in[1];
    const float* Wg  = (const float*)d_in[2];
    const float* ag  = (const float*)d_in[3];
    const float* Wt  = (const float*)d_in[4];
    const float* at  = (const float*)d_in[5];
    const float* Wo  = (const float*)d_in[6];
    const float* ao  = (const float*)d_in[7];
    float* out = (float*)d_out;

    char* ws = (char*)d_ws;
    size_t off = 0;
    auto take = [&](size_t n){ char* p = ws + off; off = (off + n + 255) & ~(size_t)255; return p; };
    float* Wh1  = (float*)take((size_t)NNODE * HIDD * 4);
    float* res  = (float*)take((size_t)NNODE * HIDD * 4);
    float* Wht  = (float*)take((size_t)NNODE * HIDD * 4);
    float* Wh2  = (float*)take((size_t)NNODE * NCLSD * 4);
    float* out2 = (float*)take((size_t)NNODE * NCLSD * 4);
    float* e1v  = (float*)take(NNODE * 4);
    float* e2v  = (float*)take(NNODE * 4);
    float* t1v  = (float*)take(NNODE * 4);
    float* t2v  = (float*)take(NNODE * 4);
    float* o1v  = (float*)take(NNODE * 4);
    float* o2v  = (float*)take(NNODE * 4);

    // layer 1: Wh1 = X @ Wg ; e1/e2 = Wh1 @ ag halves ; GAT
    k_mm<<<dim3((NNODE*HIDD)/256), dim3(256), 0, stream>>>(X, Wg, Wh1, NNODE, FEATD, HIDD);
    k_rowvec2_f32<<<dim3(NNODE/4), dim3(256), 0, stream>>>(Wh1, ag, ag + HIDD, e1v, e2v, HIDD);
    k_gat1_oracle<<<dim3(NNODE), dim3(512), 0, stream>>>(adj, e1v, e2v, Wh1, res);
    // tree scores: Wht = res @ Wt ; t1/t2 = Wht @ at halves
    k_mm<<<dim3((NNODE*HIDD)/256), dim3(256), 0, stream>>>(res, Wt, Wht, NNODE, HIDD, HIDD);
    k_rowvec2_f32<<<dim3(NNODE/4), dim3(256), 0, stream>>>(Wht, at, at + HIDD, t1v, t2v, HIDD);
    // layer 2: Wh2 = res @ Wo ; o1/o2 = Wh2 @ ao halves ; GAT + log_softmax
    k_mm<<<dim3((NNODE*NCLSD)/256), dim3(256), 0, stream>>>(res, Wo, Wh2, NNODE, HIDD, NCLSD);
    k_rowvec2_f32<<<dim3(NNODE/4), dim3(256), 0, stream>>>(Wh2, ao, ao + NCLSD, o1v, o2v, NCLSD);
    k_gat2_oracle<<<dim3(NNODE), dim3(512), 0, stream>>>(adj, o1v, o2v, t1v, t2v, Wh2, out2);
    k_logsoftmax<<<dim3(NNODE/4), dim3(256), 0, stream>>>(out2, out);
}